// Round 13
// baseline (118.508 us; speedup 1.0000x reference)
//
#include <hip/hip_runtime.h>

// ---------------------------------------------------------------------------
// TextureAnalysisModule: x (16,3,1024,1024) f32
//  k_score   : per-(patch,slice) |dx|,|dy| partial sums (round-6 verbatim)
//              + zeroes the last-block ticket counter (deterministic/replay)
//  k_finrank : 1024 blocks; finalize (parallel-load + shfl tree) writes
//              scores[p]; LAST block (atomic ticket) ranks all 1024 scores
//              (1 candidate/thread, LDS broadcast scan) -> sel[18]
//  k_output  : one wave per output row; 4 contiguous px/lane + float4 store
//  out: (2,16,3,224,224) f32
// ---------------------------------------------------------------------------

#define NSLICE 48
#define IMG    1048576

// --- K1: one block per (patch-row, slice); contiguous 32x1024 strip. -------
__global__ __launch_bounds__(256) void k_score(const float* __restrict__ x,
                                               double* __restrict__ part,
                                               unsigned* __restrict__ counter) {
  const int ph = blockIdx.x;   // patch row 0..31
  const int s  = blockIdx.y;   // slice 0..47
  const int t  = threadIdx.x;
  if (ph == 0 && s == 0 && t == 0) *counter = 0u;   // reset ticket each call

  const float* base = x + (size_t)s * IMG + (size_t)ph * 32768 + 4 * t;

  double s1x = 0.0, s2x = 0.0, s1y = 0.0, s2y = 0.0;
  const bool has_d3 = (t & 7) != 7;   // col 4t+3 is not a patch boundary

#define LD(r) (*(const float4*)(base + (size_t)(r) * 1024))
#define DX(v) { float nx = __shfl_down((v).x, 1);                              \
    float d0 = fabsf((v).y-(v).x), d1 = fabsf((v).z-(v).y),                    \
          d2 = fabsf((v).w-(v).z);                                             \
    float d3 = has_d3 ? fabsf(nx-(v).w) : 0.f;                                 \
    s1x += (double)((d0+d1)+(d2+d3));                                          \
    s2x += (double)((d0*d0+d1*d1)+(d2*d2+d3*d3)); }
#define DY(a,b) { float e0 = fabsf((b).x-(a).x), e1 = fabsf((b).y-(a).y),      \
                        e2 = fabsf((b).z-(a).z), e3 = fabsf((b).w-(a).w);      \
    s1y += (double)((e0+e1)+(e2+e3));                                          \
    s2y += (double)((e0*e0+e1*e1)+(e2*e2+e3*e3)); }

  float4 v0 = LD(0);
  for (int r = 0; r < 32; r += 8) {
    float4 w1 = LD(r + 1), w2 = LD(r + 2), w3 = LD(r + 3), w4 = LD(r + 4);
    float4 w5 = LD(r + 5), w6 = LD(r + 6), w7 = LD(r + 7);
    float4 w8;
    const bool more = (r + 8 < 32);
    if (more) w8 = LD(r + 8);
    DX(v0); DX(w1); DX(w2); DX(w3); DX(w4); DX(w5); DX(w6); DX(w7);
    DY(v0, w1); DY(w1, w2); DY(w2, w3); DY(w3, w4);
    DY(w4, w5); DY(w5, w6); DY(w6, w7);
    if (more) { DY(w7, w8); v0 = w8; }
  }
#undef LD
#undef DX
#undef DY

#pragma unroll
  for (int off = 4; off > 0; off >>= 1) {
    s1x += __shfl_down(s1x, off, 8);
    s2x += __shfl_down(s2x, off, 8);
    s1y += __shfl_down(s1y, off, 8);
    s2y += __shfl_down(s2y, off, 8);
  }
  if ((t & 7) == 0) {
    const int p = ph * 32 + (t >> 3);
    part[(size_t)(0 * NSLICE + s) * 1024 + p] = s1x;
    part[(size_t)(1 * NSLICE + s) * 1024 + p] = s2x;
    part[(size_t)(2 * NSLICE + s) * 1024 + p] = s1y;
    part[(size_t)(3 * NSLICE + s) * 1024 + p] = s2y;
  }
}

// --- K2: finalize + last-block rank. 1024 blocks x 1024 threads. -----------
// sel[0..8] = rich (ranks 1015..1023 asc), sel[9..17] = poor (ranks 0..8 asc).
__global__ __launch_bounds__(1024) void k_finrank(const double* __restrict__ part,
                                                  double* __restrict__ scores,
                                                  int* __restrict__ sel,
                                                  unsigned* __restrict__ counter) {
  const int p = blockIdx.x;
  const int t = threadIdx.x;
  __shared__ double S4[4];
  __shared__ int lastflag;

  // finalize: waves 0-3 (t<256), wave q reduces quantity q over 48 slices
  if (t < 256) {
    const int q    = t >> 6;
    const int lane = t & 63;
    double v = 0.0;
    if (lane < NSLICE)
      v = part[(size_t)(q * NSLICE + lane) * 1024 + p];
#pragma unroll
    for (int off = 32; off > 0; off >>= 1) v += __shfl_down(v, off);
    if (lane == 0) S4[q] = v;
  }
  __syncthreads();

  if (t == 0) {
    const double N = 47616.0;  // 16*3*32*31
    double mx = S4[0] / N, my = S4[2] / N;
    double vx = (S4[1] - S4[0] * S4[0] / N) / (N - 1.0);
    double vy = (S4[3] - S4[2] * S4[2] / N) / (N - 1.0);
    scores[p] = 0.25 * (mx + my) * (vx + vy);
    __threadfence();                        // release scores[p] (device scope)
    unsigned ticket = atomicAdd(counter, 1u);
    lastflag = (ticket == 1023u) ? 1 : 0;
  }
  __syncthreads();
  if (!lastflag) return;

  // last block: rank all 1024 scores (1 candidate per thread)
  __threadfence();                          // acquire others' scores
  __shared__ double sc[1024];
  const double mine = scores[t];
  sc[t] = mine;
  __syncthreads();

  int rank = 0;
  for (int j = 0; j < 1024; ++j) {
    double vj = sc[j];                      // broadcast read
    rank += (vj < mine) || (vj == mine && j < t);
  }
  if (rank < 9)          sel[9 + rank]    = t;
  else if (rank >= 1015) sel[rank - 1015] = t;
}

// --- K3: one wave per output row. 5376 blocks x 256 thr (4 waves). ---------
// Lane owns 4 CONTIGUOUS pixels; x-neighbors via 2 shfls; float4 store.
__global__ __launch_bounds__(256) void k_output(const float* __restrict__ x,
                                                const int* __restrict__ sel,
                                                float* __restrict__ out) {
  const int gb   = blockIdx.x;          // 0..5375
  const int blk  = gb / 56;             // image 0..95 = set*48 + bc
  const int y0   = (gb % 56) * 4;
  const int t    = threadIdx.x;
  const int w    = t >> 6;              // wave 0..3
  const int lane = t & 63;
  const int y    = y0 + w;              // output row 0..223

  const int set = blk / 48;
  const int bc  = blk % 48;

  __shared__ float S[4][3][96];         // per-wave staging of 3 recon rows

  // wave-uniform vertical geometry for U rows Y = y-1, y, y+1
  int   ay[3], by[3];
  float fy[3];
  bool  vy[3];
  int s0;
  {
    const int Ylo  = max(y - 1, 0);
    int numl = 3 * Ylo - 2;
    s0 = numl < 0 ? 0 : min(numl / 7, 95);
#pragma unroll
    for (int q = 0; q < 3; ++q) {
      int Y  = y - 1 + q;
      vy[q]  = ((unsigned)Y < 224u);
      int Yc = min(max(Y, 0), 223);
      int num = 3 * Yc - 2;
      int i0  = num < 0 ? 0 : num / 7;
      float fr = num < 0 ? 0.f : (float)(num - 7 * i0) * (1.f / 7.f);
      if (i0 >= 95) { i0 = 95; fr = 0.f; }
      ay[q] = i0 - s0;                       // in {0,1}
      by[q] = min(i0 + 1, 95) - s0;          // in {0,1,2}
      fy[q] = fr;
    }
  }

  // stage recon rows s0, s0+1, s0+2 (clamped) : 72 float4
  const float* src = x + (size_t)bc * IMG;
  for (int ii = lane; ii < 72; ii += 64) {
    int r    = ii / 24;
    int c4   = (ii % 24) * 4;
    int srow = min(s0 + r, 95);
    int gr = srow >> 5, si = srow & 31;
    int gc = c4 >> 5,   j  = c4 & 31;
    int pidx = sel[set * 9 + gr * 3 + gc];   // tiny, L2-hot
    const float4 v = *(const float4*)&src[(size_t)((pidx >> 5) * 32 + si) * 1024
                                          + (pidx & 31) * 32 + j];
    *(float4*)&S[w][r][c4] = v;
  }
  __syncthreads();

  // per-pixel A/M for 4 contiguous pixels xs..xs+3
  const int xs = lane << 2;                  // 0..252 (lanes >=56 clamped)
  float A[4], M[4];
#pragma unroll
  for (int k = 0; k < 4; ++k) {
    int xx = xs + k;
    int xc = min(xx, 223);
    int num = 3 * xc - 2;
    int ix0 = num < 0 ? 0 : num / 7;
    float fx = num < 0 ? 0.f : (float)(num - 7 * ix0) * (1.f / 7.f);
    if (ix0 >= 95) { ix0 = 95; fx = 0.f; }
    int ix1 = min(ix0 + 1, 95);

    float h0a = S[w][0][ix0], h0b = S[w][0][ix1];
    float h1a = S[w][1][ix0], h1b = S[w][1][ix1];
    float h2a = S[w][2][ix0], h2b = S[w][2][ix1];
    float h0 = h0a + fx * (h0b - h0a);
    float h1 = h1a + fx * (h1b - h1a);
    float h2 = h2a + fx * (h2b - h2a);

    float U3[3];
#pragma unroll
    for (int q = 0; q < 3; ++q) {
      float ha = (ay[q] == 0) ? h0 : h1;
      float hb = (by[q] == 0) ? h0 : ((by[q] == 1) ? h1 : h2);
      U3[q] = vy[q] ? (ha + fy[q] * (hb - ha)) : 0.f;
    }
    A[k] = U3[0] + U3[2];
    M[k] = U3[1];
  }

  // x-neighbors across lanes
  float aLs = __shfl_up(A[3], 1),  mLs = __shfl_up(M[3], 1);
  float aRs = __shfl_down(A[0], 1), mRs = __shfl_down(M[0], 1);

  float4 res;
  float* rp = &res.x;
#pragma unroll
  for (int k = 0; k < 4; ++k) {
    int xx = xs + k;
    float aL = (k > 0) ? A[k - 1] : aLs;
    float mL = (k > 0) ? M[k - 1] : mLs;
    float aR = (k < 3) ? A[k + 1] : aRs;
    float mR = (k < 3) ? M[k + 1] : mRs;
    if (xx == 0)   { aL = 0.f; mL = 0.f; }
    if (xx == 223) { aR = 0.f; mR = 0.f; }
    rp[k] = 3.f * (A[k] + mL + mR) - (aL + aR) - 8.f * M[k];
  }

  if (lane < 56) {
    float* o = out + (size_t)blk * (224 * 224) + (size_t)y * 224;
    *(float4*)&o[xs] = res;
  }
}

extern "C" void kernel_launch(void* const* d_in, const int* in_sizes, int n_in,
                              void* d_out, int out_size, void* d_ws, size_t ws_size,
                              hipStream_t stream) {
  const float* x = (const float*)d_in[0];
  float* out = (float*)d_out;

  double*   part    = (double*)d_ws;                       // 4*48*1024*8 = 1.5 MB
  double*   scores  = (double*)((char*)d_ws + 1572864);    // 8 KB
  int*      sel     = (int*)((char*)d_ws + 1581056);       // 72 B
  unsigned* counter = (unsigned*)((char*)d_ws + 1581184);  // 4 B

  k_score  <<<dim3(32, 48), 256, 0, stream>>>(x, part, counter);
  k_finrank<<<1024, 1024, 0, stream>>>(part, scores, sel, counter);
  k_output <<<5376, 256, 0, stream>>>(x, sel, out);
}

// Round 14
// 62.674 us; speedup vs baseline: 1.8909x; 1.8909x over previous
//
#include <hip/hip_runtime.h>

// ---------------------------------------------------------------------------
// TextureAnalysisModule: x (16,3,1024,1024) f32
//  k_score    : per-(patch,slice) |dx|,|dy| partial sums (round-6 verbatim)
//  k_finalize : one block per patch; 192 parallel loads + shfl tree
//  k_rank     : stable rank-by-counting, scatter top9/bot9 indices
//  k_output   : one wave per output row; per-wave-private LDS (no barrier);
//               4 contiguous px/lane + float4 store
//  out: (2,16,3,224,224) f32
//
//  LEDGER (measured): fusion attempts all regress on this 8-XCD chip:
//   r10 redundant-read finrank +11us; r11 grid.sync +250us; r13 last-block
//   +54us (device-scope fences). 4-dispatch pipeline is the structure.
// ---------------------------------------------------------------------------

#define NSLICE 48
#define IMG    1048576

// --- K1: one block per (patch-row, slice); contiguous 32x1024 strip. -------
__global__ __launch_bounds__(256) void k_score(const float* __restrict__ x,
                                               double* __restrict__ part) {
  const int ph = blockIdx.x;   // patch row 0..31
  const int s  = blockIdx.y;   // slice 0..47
  const int t  = threadIdx.x;
  const float* base = x + (size_t)s * IMG + (size_t)ph * 32768 + 4 * t;

  double s1x = 0.0, s2x = 0.0, s1y = 0.0, s2y = 0.0;
  const bool has_d3 = (t & 7) != 7;   // col 4t+3 is not a patch boundary

#define LD(r) (*(const float4*)(base + (size_t)(r) * 1024))
#define DX(v) { float nx = __shfl_down((v).x, 1);                              \
    float d0 = fabsf((v).y-(v).x), d1 = fabsf((v).z-(v).y),                    \
          d2 = fabsf((v).w-(v).z);                                             \
    float d3 = has_d3 ? fabsf(nx-(v).w) : 0.f;                                 \
    s1x += (double)((d0+d1)+(d2+d3));                                          \
    s2x += (double)((d0*d0+d1*d1)+(d2*d2+d3*d3)); }
#define DY(a,b) { float e0 = fabsf((b).x-(a).x), e1 = fabsf((b).y-(a).y),      \
                        e2 = fabsf((b).z-(a).z), e3 = fabsf((b).w-(a).w);      \
    s1y += (double)((e0+e1)+(e2+e3));                                          \
    s2y += (double)((e0*e0+e1*e1)+(e2*e2+e3*e3)); }

  float4 v0 = LD(0);
  for (int r = 0; r < 32; r += 8) {
    float4 w1 = LD(r + 1), w2 = LD(r + 2), w3 = LD(r + 3), w4 = LD(r + 4);
    float4 w5 = LD(r + 5), w6 = LD(r + 6), w7 = LD(r + 7);
    float4 w8;
    const bool more = (r + 8 < 32);
    if (more) w8 = LD(r + 8);
    DX(v0); DX(w1); DX(w2); DX(w3); DX(w4); DX(w5); DX(w6); DX(w7);
    DY(v0, w1); DY(w1, w2); DY(w2, w3); DY(w3, w4);
    DY(w4, w5); DY(w5, w6); DY(w6, w7);
    if (more) { DY(w7, w8); v0 = w8; }
  }
#undef LD
#undef DX
#undef DY

#pragma unroll
  for (int off = 4; off > 0; off >>= 1) {
    s1x += __shfl_down(s1x, off, 8);
    s2x += __shfl_down(s2x, off, 8);
    s1y += __shfl_down(s1y, off, 8);
    s2y += __shfl_down(s2y, off, 8);
  }
  if ((t & 7) == 0) {
    const int p = ph * 32 + (t >> 3);
    part[(size_t)(0 * NSLICE + s) * 1024 + p] = s1x;
    part[(size_t)(1 * NSLICE + s) * 1024 + p] = s2x;
    part[(size_t)(2 * NSLICE + s) * 1024 + p] = s1y;
    part[(size_t)(3 * NSLICE + s) * 1024 + p] = s2y;
  }
}

// --- K2: one block per patch; wave q reduces quantity q over 48 slices. ----
__global__ __launch_bounds__(256) void k_finalize(const double* __restrict__ part,
                                                  double* __restrict__ scores) {
  const int p    = blockIdx.x;
  const int t    = threadIdx.x;
  const int q    = t >> 6;
  const int lane = t & 63;

  double v = 0.0;
  if (lane < NSLICE)
    v = part[(size_t)(q * NSLICE + lane) * 1024 + p];

#pragma unroll
  for (int off = 32; off > 0; off >>= 1) v += __shfl_down(v, off);

  __shared__ double S[4];
  if (lane == 0) S[q] = v;
  __syncthreads();

  if (t == 0) {
    const double N = 47616.0;  // 16*3*32*31
    double mx = S[0] / N, my = S[2] / N;
    double vx = (S[1] - S[0] * S[0] / N) / (N - 1.0);
    double vy = (S[3] - S[2] * S[2] / N) / (N - 1.0);
    scores[p] = 0.25 * (mx + my) * (vx + vy);
  }
}

// --- K3: stable rank; 8 lanes per candidate, 32 candidates per block. ------
__global__ __launch_bounds__(256) void k_rank(const double* __restrict__ scores,
                                              int* __restrict__ sel) {
  __shared__ double sc[1024];
  const int t = threadIdx.x;
  for (int i = t; i < 1024; i += 256) sc[i] = scores[i];
  __syncthreads();

  const int c = blockIdx.x * 32 + (t >> 3);
  const double mine = sc[c];
  int rank = 0;
  for (int j = (t & 7); j < 1024; j += 8) {
    double vj = sc[j];
    rank += (vj < mine) || (vj == mine && j < c);
  }
#pragma unroll
  for (int off = 4; off > 0; off >>= 1) rank += __shfl_down(rank, off, 8);
  if ((t & 7) == 0) {
    if (rank < 9)          sel[9 + rank]    = c;
    else if (rank >= 1015) sel[rank - 1015] = c;
  }
}

// --- K4: one wave per output row; wave-private LDS, NO block barrier. ------
__global__ __launch_bounds__(256) void k_output(const float* __restrict__ x,
                                                const int* __restrict__ sel,
                                                float* __restrict__ out) {
  const int gb   = blockIdx.x;          // 0..5375
  const int blk  = gb / 56;             // image 0..95 = set*48 + bc
  const int y0   = (gb % 56) * 4;
  const int t    = threadIdx.x;
  const int w    = t >> 6;              // wave 0..3
  const int lane = t & 63;
  const int y    = y0 + w;              // output row 0..223

  const int set = blk / 48;
  const int bc  = blk % 48;

  __shared__ float S[4][3][96];         // per-wave staging (wave-private)

  // wave-uniform vertical geometry for U rows Y = y-1, y, y+1
  int   ay[3], by[3];
  float fy[3];
  bool  vy[3];
  int s0;
  {
    const int Ylo  = max(y - 1, 0);
    int numl = 3 * Ylo - 2;
    s0 = numl < 0 ? 0 : min(numl / 7, 95);
#pragma unroll
    for (int q = 0; q < 3; ++q) {
      int Y  = y - 1 + q;
      vy[q]  = ((unsigned)Y < 224u);
      int Yc = min(max(Y, 0), 223);
      int num = 3 * Yc - 2;
      int i0  = num < 0 ? 0 : num / 7;
      float fr = num < 0 ? 0.f : (float)(num - 7 * i0) * (1.f / 7.f);
      if (i0 >= 95) { i0 = 95; fr = 0.f; }
      ay[q] = i0 - s0;                       // in {0,1}
      by[q] = min(i0 + 1, 95) - s0;          // in {0,1,2}
      fy[q] = fr;
    }
  }

  // stage recon rows s0, s0+1, s0+2 (clamped): lane ii and ii+64 of 72 jobs
  const float* src = x + (size_t)bc * IMG;
#pragma unroll
  for (int half = 0; half < 2; ++half) {
    int ii = lane + half * 64;
    if (ii < 72) {
      int r    = ii / 24;
      int c4   = (ii % 24) * 4;
      int srow = min(s0 + r, 95);
      int gr = srow >> 5, si = srow & 31;
      int gc = c4 >> 5,   j  = c4 & 31;
      int pidx = sel[set * 9 + gr * 3 + gc];   // 72 B, L2-hot
      const float4 v = *(const float4*)&src[(size_t)((pidx >> 5) * 32 + si) * 1024
                                            + (pidx & 31) * 32 + j];
      *(float4*)&S[w][r][c4] = v;
    }
  }
  // no __syncthreads: S[w] is wave-private; lgkmcnt ordering covers RAW.

  // per-pixel A/M for 4 contiguous pixels xs..xs+3
  const int xs = lane << 2;                  // 0..252 (lanes >=56 idle at store)
  float A[4], M[4];
#pragma unroll
  for (int k = 0; k < 4; ++k) {
    int xx = xs + k;
    int xc = min(xx, 223);
    int num = 3 * xc - 2;
    int ix0 = num < 0 ? 0 : num / 7;
    float fx = num < 0 ? 0.f : (float)(num - 7 * ix0) * (1.f / 7.f);
    if (ix0 >= 95) { ix0 = 95; fx = 0.f; }
    int ix1 = min(ix0 + 1, 95);

    float h0a = S[w][0][ix0], h0b = S[w][0][ix1];
    float h1a = S[w][1][ix0], h1b = S[w][1][ix1];
    float h2a = S[w][2][ix0], h2b = S[w][2][ix1];
    float h0 = h0a + fx * (h0b - h0a);
    float h1 = h1a + fx * (h1b - h1a);
    float h2 = h2a + fx * (h2b - h2a);

    float U3[3];
#pragma unroll
    for (int q = 0; q < 3; ++q) {
      float ha = (ay[q] == 0) ? h0 : h1;
      float hb = (by[q] == 0) ? h0 : ((by[q] == 1) ? h1 : h2);
      U3[q] = vy[q] ? (ha + fy[q] * (hb - ha)) : 0.f;
    }
    A[k] = U3[0] + U3[2];
    M[k] = U3[1];
  }

  // x-neighbors across lanes
  float aLs = __shfl_up(A[3], 1),   mLs = __shfl_up(M[3], 1);
  float aRs = __shfl_down(A[0], 1), mRs = __shfl_down(M[0], 1);

  float4 res;
  float* rp = &res.x;
#pragma unroll
  for (int k = 0; k < 4; ++k) {
    int xx = xs + k;
    float aL = (k > 0) ? A[k - 1] : aLs;
    float mL = (k > 0) ? M[k - 1] : mLs;
    float aR = (k < 3) ? A[k + 1] : aRs;
    float mR = (k < 3) ? M[k + 1] : mRs;
    if (xx == 0)   { aL = 0.f; mL = 0.f; }
    if (xx == 223) { aR = 0.f; mR = 0.f; }
    rp[k] = 3.f * (A[k] + mL + mR) - (aL + aR) - 8.f * M[k];
  }

  if (lane < 56) {
    float* o = out + (size_t)blk * (224 * 224) + (size_t)y * 224;
    *(float4*)&o[xs] = res;
  }
}

extern "C" void kernel_launch(void* const* d_in, const int* in_sizes, int n_in,
                              void* d_out, int out_size, void* d_ws, size_t ws_size,
                              hipStream_t stream) {
  const float* x = (const float*)d_in[0];
  float* out = (float*)d_out;

  double* part   = (double*)d_ws;                          // 4*48*1024*8 = 1.5 MB
  double* scores = (double*)((char*)d_ws + 1572864);       // 8 KB
  int*    sel    = (int*)((char*)d_ws + 1581056);          // 72 B

  k_score   <<<dim3(32, 48), 256, 0, stream>>>(x, part);
  k_finalize<<<1024, 256, 0, stream>>>(part, scores);
  k_rank    <<<32, 256, 0, stream>>>(scores, sel);
  k_output  <<<5376, 256, 0, stream>>>(x, sel, out);
}